// Round 8
// baseline (242.140 us; speedup 1.0000x reference)
//
#include <hip/hip_runtime.h>

typedef __attribute__((ext_vector_type(8))) short short8;
typedef __attribute__((ext_vector_type(4))) float f32x4;
typedef __attribute__((ext_vector_type(16))) float f32x16;

#define DEV static __device__ __forceinline__

DEV float bf2f(unsigned short u) {
  union { unsigned int u32; float f; } v; v.u32 = ((unsigned int)u) << 16; return v.f;
}
DEV unsigned short f2bf(float f) {
  union { float f; unsigned int u; } v; v.f = f;
  unsigned int r = v.u + 0x7fffu + ((v.u >> 16) & 1u);
  return (unsigned short)(r >> 16);
}
DEV unsigned cvtpk(float lo, float hi) {
  unsigned r;
  asm("v_cvt_pk_bf16_f32 %0, %1, %2" : "=v"(r) : "v"(lo), "v"(hi));
  return r;
}
DEV void plswap(unsigned &a, unsigned &b) {
  asm("v_permlane32_swap_b32 %0, %1" : "+v"(a), "+v"(b));
}
DEV short8 mk8(unsigned a, unsigned b, unsigned c, unsigned d) {
  union { unsigned u[4]; short8 v; } x;
  x.u[0] = a; x.u[1] = b; x.u[2] = c; x.u[3] = d; return x.v;
}

// async global->LDS, 16B per lane; LDS dest is wave-uniform base + lane*16
#define GLL16(g, l) __builtin_amdgcn_global_load_lds( \
    (const __attribute__((address_space(1))) void*)(g), \
    (__attribute__((address_space(3))) void*)(l), 16, 0, 0)

constexpr int D  = 512;
constexpr int BT = 32768;   // B*T rows

// ---------------- K1: fp32 -> bf16 conversion (x, Wq|Wk|Wv concat, Wo) ----------------
__global__ __launch_bounds__(256) void k_convert(
    const float* __restrict__ x, const float* __restrict__ Wq, const float* __restrict__ Wk,
    const float* __restrict__ Wv, const float* __restrict__ Wo,
    unsigned short* __restrict__ xb, unsigned short* __restrict__ wqkv,
    unsigned short* __restrict__ wo_b) {
  int idx = blockIdx.x * 256 + threadIdx.x;
  const int NX4 = (BT * D) / 4;      // 4,194,304
  const float* src; unsigned short* dst; size_t i4;
  if (idx < NX4) {
    src = x; dst = xb; i4 = (size_t)idx * 4;
  } else {
    int t = idx - NX4;
    int w = t >> 16;                 // NW4 = 512*512/4 = 65536
    int within = t & 65535;
    src = (w == 0) ? Wq : (w == 1) ? Wk : (w == 2) ? Wv : Wo;
    dst = (w < 3) ? (wqkv + (size_t)w * D * D) : wo_b;
    i4 = (size_t)within * 4;
  }
  float4 v = *(const float4*)(src + i4);
  ushort4 o; o.x = f2bf(v.x); o.y = f2bf(v.y); o.z = f2bf(v.z); o.w = f2bf(v.w);
  *(ushort4*)(dst + i4) = o;
}

// ---------------- GEMM v3: C[M,N] = A[M,512] x B[N,512]^T ----------------
// 128(M) x 256(N) tile, BK=32, 8 waves (2x4), 512 threads, THREE LDS buffers,
// prefetch depth 2, counted vmcnt(3) steady state (T4), conflict-free 4-slot XOR swizzle.
// EPI 0: C -> O0 row-major. EPI 1 (NBLK=6): nb 0-1 Q (pre-scaled by 0.125*log2e for the
// exp2-domain softmax in k_attn), 2-3 K, 4-5 Vt-scatter.
template<int NBLK, int EPI>
__global__ __launch_bounds__(512, 4) void k_gemm(
    const unsigned short* __restrict__ A, const unsigned short* __restrict__ Bm,
    unsigned short* __restrict__ O0, unsigned short* __restrict__ O1,
    unsigned short* __restrict__ O2) {
  __shared__ unsigned short Ash[3][128 * 32];   // 24 KB
  __shared__ unsigned short Bsh[3][256 * 32];   // 48 KB
  const int tid = threadIdx.x;
  const int lane = tid & 63, w = tid >> 6;      // 8 waves
  const int lr = lane & 15, lg = lane >> 4;
  const int cpx = gridDim.x >> 3;
  const int bid = blockIdx.x;
  const int work = (bid & 7) * cpx + (bid >> 3);
  const int nb = work % NBLK, mb = work / NBLK;
  const int m0 = mb * 128, n0 = nb * 256;
  const int wr = w >> 2, wc = w & 3;            // wave tile: 64 rows x 64 cols

  const int sr = lane >> 2;
  const int sg8 = ((lane & 3) ^ ((lane >> 3) & 3)) * 8;
  const unsigned short* gA  = A  + (size_t)(m0 + w * 16 + sr) * D + sg8;
  const unsigned short* gB0 = Bm + (size_t)(n0 + w * 16 + sr) * D + sg8;
  const unsigned short* gB1 = Bm + (size_t)(n0 + 128 + w * 16 + sr) * D + sg8;

  auto stage = [&](int kt, int b) {
    GLL16(gA  + kt * 32, &Ash[b][w * 512]);
    GLL16(gB0 + kt * 32, &Bsh[b][w * 512]);
    GLL16(gB1 + kt * 32, &Bsh[b][(128 + w * 16) * 32]);
  };

  f32x4 acc[4][4];
  #pragma unroll
  for (int m = 0; m < 4; ++m)
    #pragma unroll
    for (int n = 0; n < 4; ++n) acc[m][n] = (f32x4){0.f, 0.f, 0.f, 0.f};

  stage(0, 0);
  stage(1, 1);

  const int rdsw = (lg ^ ((lr >> 1) & 3)) * 8;   // conflict-free read slot

#define GSTEP(KT, WN) { \
    asm volatile("s_waitcnt vmcnt(" #WN ")" ::: "memory"); \
    __builtin_amdgcn_s_barrier(); \
    if ((KT) + 2 < 16) stage((KT) + 2, ((KT) + 2) % 3); \
    const unsigned short* Ac = Ash[(KT) % 3]; \
    const unsigned short* Bc = Bsh[(KT) % 3]; \
    short8 af[4], bf[4]; \
    _Pragma("unroll") \
    for (int m = 0; m < 4; ++m) \
      af[m] = *(const short8*)&Ac[(wr * 64 + m * 16 + lr) * 32 + rdsw]; \
    _Pragma("unroll") \
    for (int n = 0; n < 4; ++n) \
      bf[n] = *(const short8*)&Bc[(wc * 64 + n * 16 + lr) * 32 + rdsw]; \
    __builtin_amdgcn_s_setprio(1); \
    _Pragma("unroll") \
    for (int m = 0; m < 4; ++m) \
      _Pragma("unroll") \
      for (int n = 0; n < 4; ++n) \
        acc[m][n] = __builtin_amdgcn_mfma_f32_16x16x32_bf16(af[m], bf[n], acc[m][n], 0, 0, 0); \
    __builtin_amdgcn_s_setprio(0); \
  }

  GSTEP(0, 3)  GSTEP(1, 3)  GSTEP(2, 3)  GSTEP(3, 3)
  GSTEP(4, 3)  GSTEP(5, 3)  GSTEP(6, 3)  GSTEP(7, 3)
  GSTEP(8, 3)  GSTEP(9, 3)  GSTEP(10, 3) GSTEP(11, 3)
  GSTEP(12, 3) GSTEP(13, 3) GSTEP(14, 3) GSTEP(15, 0)
#undef GSTEP

  // ---- epilogue ----
  if (EPI == 1 && nb >= 4) {
    #pragma unroll
    for (int m = 0; m < 4; ++m) {
      #pragma unroll
      for (int n = 0; n < 4; ++n) {
        int e = (n0 - 1024) + wc * 64 + n * 16 + lr;
        int grow = m0 + wr * 64 + m * 16 + lg * 4;
        int bc = grow >> 9, key = grow & 511;
        ushort4 pk;
        pk.x = f2bf(acc[m][n][0]); pk.y = f2bf(acc[m][n][1]);
        pk.z = f2bf(acc[m][n][2]); pk.w = f2bf(acc[m][n][3]);
        *(ushort4*)&O2[(size_t)(bc * 512 + e) * 512 + key] = pk;
      }
    }
  } else {
    unsigned short* Od = O0;
    int cshift = 0;
    // Q output pre-scale: 0.125 (1/sqrt(64)) * log2(e) for exp2-domain softmax
    float cs = (EPI == 1 && nb < 2) ? 0.1803368801f : 1.0f;
    if (EPI == 1 && nb >= 2) { Od = O1; cshift = 512; }
    #pragma unroll
    for (int m = 0; m < 4; ++m) {
      #pragma unroll
      for (int n = 0; n < 4; ++n) {
        int col = n0 + wc * 64 + n * 16 + lr - cshift;
        #pragma unroll
        for (int r = 0; r < 4; ++r) {
          int row = m0 + wr * 64 + m * 16 + lg * 4 + r;
          Od[(size_t)row * D + col] = f2bf(acc[m][n][r] * cs);
        }
      }
    }
  }
}

// ---------------- K3: flash-style local attention, swapped 32x32 MFMA ----------------
// grid = 1024 = 64 chunks x 8 heads x 2 q-halves; block = 512 (8 waves x 32 q-rows).
// exp2-domain softmax (Q pre-scaled), defer-max THR=8 (T13), row-spreading LDS swizzle
// f(row) = (row + (row>>3)) & 7 (conflict-free b128 reads).
__global__ __launch_bounds__(512, 4) void k_attn(
    const unsigned short* __restrict__ Q, const unsigned short* __restrict__ K,
    const unsigned short* __restrict__ Vt, unsigned short* __restrict__ attn_out) {
  __shared__ char lds[3][16384];   // buf: [0,8K) K-tile [64keys][64d], [8K,16K) V-tile [64e][64k]
  const int tid = threadIdx.x;
  const int lane = tid & 63, w = tid >> 6;
  const int l31 = lane & 31, hl = lane >> 5;
  int work = ((blockIdx.x & 7) << 7) + (blockIdx.x >> 3);   // XCD-chunked swizzle (1024%8==0)
  int qh = work & 1, h = (work >> 1) & 7, bc = work >> 4;
  int qbase = bc * 512 + qh * 256 + w * 32;

  // Q B-frags: B[q=l31][k = ks*16 + hl*8 + j]  (Q pre-scaled by 0.125*log2e in k_gemm)
  short8 qf[4];
  {
    const unsigned short* qp = Q + (size_t)(qbase + l31) * D + h * 64 + hl * 8;
    #pragma unroll
    for (int ks = 0; ks < 4; ++ks) qf[ks] = *(const short8*)(qp + ks * 16);
  }

  // staging: LDS[row][slot] = G[row][slot ^ f(row)], f(row) = (row + row>>3) & 7
  const int lr3 = lane >> 3;
  const int srow = w * 8 + lr3;                      // 0..63
  const int sq = (lane & 7) ^ ((lr3 + w) & 7);       // source quad = slot ^ f(row)
  const unsigned short* gK = K  + (size_t)(bc * 512 + srow) * D + h * 64 + sq * 8;
  const unsigned short* gV = Vt + (size_t)(bc * 512 + h * 64 + srow) * D + sq * 8;
  auto STAGE = [&](int T, int B) {
    GLL16(gK + (size_t)(T) * 64 * D, &lds[B][w * 1024]);
    GLL16(gV + (T) * 64,             &lds[B][8192 + w * 1024]);
  };

  f32x16 oA, oB;
  #pragma unroll
  for (int i = 0; i < 16; ++i) { oA[i] = 0.f; oB[i] = 0.f; }
  float mrun = -3e38f, lrun = 0.f;
  const int f0 = (l31 + (l31 >> 3)) & 7;   // f(row l31)
  const int f1 = (f0 + 4) & 7;             // f(row 32+l31)

  STAGE(0, 0);
  STAGE(1, 1);

  #pragma unroll
  for (int t = 0; t < 8; ++t) {
    if (t == 0 || t == 7) asm volatile("s_waitcnt vmcnt(0)" ::: "memory");
    else                  asm volatile("s_waitcnt vmcnt(2)" ::: "memory");
    __builtin_amdgcn_s_barrier();
    if (t < 6) STAGE(t + 2, (t + 2) % 3);
    const char* kb = lds[t % 3];
    const char* vb = lds[t % 3] + 8192;

    // ---- QK^T swapped: S^T[key][q] = mfma(A=K, B=Q) ----
    f32x16 sA, sB;
    #pragma unroll
    for (int i = 0; i < 16; ++i) { sA[i] = 0.f; sB[i] = 0.f; }
    #pragma unroll
    for (int ks = 0; ks < 4; ++ks) {
      int c = ks * 2 + hl;
      short8 kf0 = *(const short8*)(kb + l31 * 128 + ((c ^ f0) << 4));
      short8 kf1 = *(const short8*)(kb + (32 + l31) * 128 + ((c ^ f1) << 4));
      sA = __builtin_amdgcn_mfma_f32_32x32x16_bf16(kf0, qf[ks], sA, 0, 0, 0);
      sB = __builtin_amdgcn_mfma_f32_32x32x16_bf16(kf1, qf[ks], sB, 0, 0, 0);
    }

    // ---- online softmax, exp2 domain (lane owns q = l31; partner lane^32 = other keys) ----
    float pm = fmaxf(sA[0], sA[1]);
    #pragma unroll
    for (int i = 2; i < 16; i += 2) pm = fmaxf(pm, fmaxf(sA[i], sA[i + 1]));   // v_max3
    #pragma unroll
    for (int i = 0; i < 16; i += 2) pm = fmaxf(pm, fmaxf(sB[i], sB[i + 1]));
    pm = fmaxf(pm, __shfl_xor(pm, 32));
    if (!__all(pm - mrun <= 8.f)) {     // defer-max (T13): rescale only on real growth
      float mnew = fmaxf(mrun, pm);
      float alpha = exp2f(mrun - mnew); // first tile: exp2(-inf) = 0
      mrun = mnew;
      lrun *= alpha;
      #pragma unroll
      for (int i = 0; i < 16; ++i) { oA[i] *= alpha; oB[i] *= alpha; }
    }
    float ls = 0.f;
    #pragma unroll
    for (int i = 0; i < 16; ++i) { float p = exp2f(sA[i] - mrun); sA[i] = p; ls += p; }
    #pragma unroll
    for (int i = 0; i < 16; ++i) { float p = exp2f(sB[i] - mrun); sB[i] = p; ls += p; }
    ls += __shfl_xor(ls, 32);
    lrun += ls;

    // ---- P repack to PV fragments: cvt_pk + permlane32_swap (T12) ----
    unsigned dA[8], dB[8];
    #pragma unroll
    for (int i = 0; i < 8; ++i) {
      dA[i] = cvtpk(sA[2 * i], sA[2 * i + 1]);
      dB[i] = cvtpk(sB[2 * i], sB[2 * i + 1]);
    }
    plswap(dA[0], dA[2]); plswap(dA[1], dA[3]);
    plswap(dA[4], dA[6]); plswap(dA[5], dA[7]);
    plswap(dB[0], dB[2]); plswap(dB[1], dB[3]);
    plswap(dB[4], dB[6]); plswap(dB[5], dB[7]);
    short8 pf[4] = { mk8(dA[0], dA[1], dA[2], dA[3]), mk8(dA[4], dA[5], dA[6], dA[7]),
                     mk8(dB[0], dB[1], dB[2], dB[3]), mk8(dB[4], dB[5], dB[6], dB[7]) };

    // ---- PV swapped: O^T[e][q] += mfma(A=V, B=P) ----
    #pragma unroll
    for (int k4 = 0; k4 < 4; ++k4) {
      int c = k4 * 2 + hl;
      short8 vf0 = *(const short8*)(vb + l31 * 128 + ((c ^ f0) << 4));
      short8 vf1 = *(const short8*)(vb + (32 + l31) * 128 + ((c ^ f1) << 4));
      oA = __builtin_amdgcn_mfma_f32_32x32x16_bf16(vf0, pf[k4], oA, 0, 0, 0);
      oB = __builtin_amdgcn_mfma_f32_32x32x16_bf16(vf1, pf[k4], oB, 0, 0, 0);
    }
  }

  // ---- epilogue: normalize, transpose O^T -> O via per-wave LDS region ----
  __syncthreads();                      // all waves done reading KV bufs
  float inv = 1.f / lrun;
  const int x7 = l31 & 7;
  char* tr = &lds[0][0] + w * 4096;     // [32 q][64 e] bf16, XOR-swizzled rows
  #pragma unroll
  for (int r = 0; r < 16; ++r) {
    int e0 = (r & 3) + 8 * (r >> 2) + 4 * hl;
    *(unsigned short*)(tr + ((l31 * 128 + e0 * 2) ^ (x7 << 4)))        = f2bf(oA[r] * inv);
    *(unsigned short*)(tr + ((l31 * 128 + (32 + e0) * 2) ^ (x7 << 4))) = f2bf(oB[r] * inv);
  }
  unsigned short* op = attn_out + (size_t)(qbase + l31) * D + h * 64 + hl * 32;
  #pragma unroll
  for (int s = 0; s < 4; ++s) {
    int slot = (hl * 4 + s) ^ x7;
    short8 v = *(const short8*)(tr + l31 * 128 + slot * 16);
    *(short8*)(op + s * 8) = v;
  }
}

// ---------------- K4b: per-chunk mean -> summaries fp32 [64][512] ----------------
__global__ __launch_bounds__(256) void k_mean(const unsigned short* __restrict__ lout,
                                              float* __restrict__ summ) {
  int bc = blockIdx.x;
  int col = blockIdx.y * 256 + threadIdx.x;
  const unsigned short* p = lout + (size_t)bc * 512 * 512 + col;
  float s = 0.f;
  #pragma unroll 8
  for (int r = 0; r < 512; ++r) s += bf2f(p[(size_t)r * 512]);
  summ[bc * 512 + col] = s * (1.f / 512.f);
}

// ---------------- K5a: sg = summaries @ Wg.T (fp32, tiny) ----------------
__global__ __launch_bounds__(256) void k_sg(const float* __restrict__ summ,
                                            const float* __restrict__ Wg,
                                            float* __restrict__ sg) {
  __shared__ float srow[512];
  int m = blockIdx.x >> 1, half = blockIdx.x & 1;
  for (int i = threadIdx.x; i < 512; i += 256) srow[i] = summ[m * 512 + i];
  __syncthreads();
  int n = half * 256 + threadIdx.x;
  const float* wr = Wg + (size_t)n * 512;
  float s = 0.f;
  #pragma unroll 8
  for (int kk = 0; kk < 512; ++kk) s += srow[kk] * wr[kk];
  sg[m * 512 + n] = s;
}

// ---------------- K5b: cross-chunk attention (fp32, tiny) ----------------
__global__ __launch_bounds__(256) void k_gattn(const float* __restrict__ sg,
                                               float* __restrict__ gctx) {
  __shared__ float qs[32][64];
  __shared__ float sc[32][32];
  int b = blockIdx.x >> 3, h = blockIdx.x & 7;
  int tid = threadIdx.x;
  for (int i = tid; i < 2048; i += 256) {
    int r = i >> 6, e = i & 63;
    qs[r][e] = sg[(size_t)(b * 32 + r) * 512 + h * 64 + e];
  }
  __syncthreads();
  for (int p = tid; p < 1024; p += 256) {
    int qi = p >> 5, ki = p & 31;
    float s = 0.f;
    #pragma unroll 8
    for (int e = 0; e < 64; ++e) s += qs[qi][e] * qs[ki][e];
    sc[qi][ki] = s * 0.125f;
  }
  __syncthreads();
  if (tid < 32) {
    float mx = -1e30f;
    for (int k2 = 0; k2 < 32; ++k2) mx = fmaxf(mx, sc[tid][k2]);
    float sm = 0.f;
    for (int k2 = 0; k2 < 32; ++k2) { float p = __expf(sc[tid][k2] - mx); sc[tid][k2] = p; sm += p; }
    float iv = 1.f / sm;
    for (int k2 = 0; k2 < 32; ++k2) sc[tid][k2] *= iv;
  }
  __syncthreads();
  for (int i = tid; i < 2048; i += 256) {
    int r = i >> 6, e = i & 63;
    float o = 0.f;
    #pragma unroll 8
    for (int k2 = 0; k2 < 32; ++k2) o += sc[r][k2] * qs[k2][e];
    gctx[(size_t)(b * 32 + r) * 512 + h * 64 + e] = o;
  }
}

// ---------------- K6: out = local_out + broadcast(gctx), fp32 output ----------------
__global__ __launch_bounds__(256) void k_final(const unsigned short* __restrict__ lout,
                                               const float* __restrict__ gctx,
                                               float* __restrict__ out) {
  size_t idx = (size_t)blockIdx.x * 256 + threadIdx.x;
  size_t i = idx * 4;
  int c = (int)(i & 511);
  int bcg = (int)(i >> 18);
  ushort4 lv = *(const ushort4*)(lout + i);
  float4 g = *(const float4*)(gctx + (size_t)bcg * 512 + c);
  float4 o;
  o.x = bf2f(lv.x) + g.x;
  o.y = bf2f(lv.y) + g.y;
  o.z = bf2f(lv.z) + g.z;
  o.w = bf2f(lv.w) + g.w;
  *(float4*)(out + i) = o;
}

extern "C" void kernel_launch(void* const* d_in, const int* in_sizes, int n_in,
                              void* d_out, int out_size, void* d_ws, size_t ws_size,
                              hipStream_t stream) {
  const float* x  = (const float*)d_in[0];
  const float* Wq = (const float*)d_in[1];
  const float* Wk = (const float*)d_in[2];
  const float* Wv = (const float*)d_in[3];
  const float* Wo = (const float*)d_in[4];
  const float* Wg = (const float*)d_in[5];
  float* out = (float*)d_out;

  char* ws = (char*)d_ws;
  unsigned short* xb   = (unsigned short*)(ws);                 // 32 MB  [A]
  unsigned short* q    = (unsigned short*)(ws + 33554432);      // 32 MB  [B]
  unsigned short* kb   = (unsigned short*)(ws + 67108864);      // 32 MB  [C]
  unsigned short* vt   = (unsigned short*)(ws + 100663296);     // 32 MB  [D]
  unsigned short* wqkv = (unsigned short*)(ws + 134217728);     // 1.5 MB
  unsigned short* wo_b = (unsigned short*)(ws + 135790592);     // 0.5 MB
  float* summ = (float*)(ws + 136314880);                       // 128 KB
  float* sgp  = (float*)(ws + 136445952);                       // 128 KB
  float* gctx = (float*)(ws + 136577024);                       // 128 KB
  unsigned short* attn_out = xb;   // region A reused (xb dead after k_qkv)
  unsigned short* local_bf = q;    // region B reused (q dead after k_attn)

  k_convert<<<17408, 256, 0, stream>>>(x, Wq, Wk, Wv, Wo, xb, wqkv, wo_b);
  // QKV: M=32768, N=1536 -> 256 x 6 = 1536 blocks, 512 threads
  k_gemm<6, 1><<<1536, 512, 0, stream>>>(xb, wqkv, q, kb, vt);
  k_attn<<<1024, 512, 0, stream>>>(q, kb, vt, attn_out);
  // Wo: M=32768, N=512 -> 256 x 2 = 512 blocks, 512 threads
  k_gemm<2, 0><<<512, 512, 0, stream>>>(attn_out, wo_b, local_bf, nullptr, nullptr);
  k_mean<<<dim3(64, 2), 256, 0, stream>>>(local_bf, summ);
  k_sg<<<128, 256, 0, stream>>>(summ, Wg, sgp);
  k_gattn<<<16, 256, 0, stream>>>(sgp, gctx);
  k_final<<<16384, 256, 0, stream>>>(local_bf, gctx, out);
}

// Round 10
// 231.548 us; speedup vs baseline: 1.0457x; 1.0457x over previous
//
#include <hip/hip_runtime.h>

typedef __attribute__((ext_vector_type(8))) short short8;
typedef __attribute__((ext_vector_type(4))) float f32x4;
typedef __attribute__((ext_vector_type(16))) float f32x16;

#define DEV static __device__ __forceinline__

DEV float bf2f(unsigned short u) {
  union { unsigned int u32; float f; } v; v.u32 = ((unsigned int)u) << 16; return v.f;
}
DEV unsigned short f2bf(float f) {
  union { float f; unsigned int u; } v; v.f = f;
  unsigned int r = v.u + 0x7fffu + ((v.u >> 16) & 1u);
  return (unsigned short)(r >> 16);
}
DEV unsigned cvtpk(float lo, float hi) {
  unsigned r;
  asm("v_cvt_pk_bf16_f32 %0, %1, %2" : "=v"(r) : "v"(lo), "v"(hi));
  return r;
}
DEV void plswap(unsigned &a, unsigned &b) {
  asm("v_permlane32_swap_b32 %0, %1" : "+v"(a), "+v"(b));
}
DEV short8 mk8(unsigned a, unsigned b, unsigned c, unsigned d) {
  union { unsigned u[4]; short8 v; } x;
  x.u[0] = a; x.u[1] = b; x.u[2] = c; x.u[3] = d; return x.v;
}
// raw v_exp_f32 (= 2^x). libm exp2f expands to a slow denormal-safe sequence (r7 lesson);
// gfx9-lineage VALU is interlocked so the asm result is safe to consume immediately.
DEV float fexp2(float x) {
  float r;
  asm("v_exp_f32 %0, %1" : "=v"(r) : "v"(x));
  return r;
}

// async global->LDS, 16B per lane; LDS dest is wave-uniform base + lane*16
#define GLL16(g, l) __builtin_amdgcn_global_load_lds( \
    (const __attribute__((address_space(1))) void*)(g), \
    (__attribute__((address_space(3))) void*)(l), 16, 0, 0)

constexpr int D  = 512;
constexpr int BT = 32768;   // B*T rows

// ---------------- K1: fp32 -> bf16 conversion (x, Wq|Wk|Wv concat, Wo) ----------------
__global__ __launch_bounds__(256) void k_convert(
    const float* __restrict__ x, const float* __restrict__ Wq, const float* __restrict__ Wk,
    const float* __restrict__ Wv, const float* __restrict__ Wo,
    unsigned short* __restrict__ xb, unsigned short* __restrict__ wqkv,
    unsigned short* __restrict__ wo_b) {
  int idx = blockIdx.x * 256 + threadIdx.x;
  const int NX4 = (BT * D) / 4;      // 4,194,304
  const float* src; unsigned short* dst; size_t i4;
  if (idx < NX4) {
    src = x; dst = xb; i4 = (size_t)idx * 4;
  } else {
    int t = idx - NX4;
    int w = t >> 16;                 // NW4 = 512*512/4 = 65536
    int within = t & 65535;
    src = (w == 0) ? Wq : (w == 1) ? Wk : (w == 2) ? Wv : Wo;
    dst = (w < 3) ? (wqkv + (size_t)w * D * D) : wo_b;
    i4 = (size_t)within * 4;
  }
  float4 v = *(const float4*)(src + i4);
  ushort4 o; o.x = f2bf(v.x); o.y = f2bf(v.y); o.z = f2bf(v.z); o.w = f2bf(v.w);
  *(ushort4*)(dst + i4) = o;
}

// ---------------- GEMM v3: C[M,N] = A[M,512] x B[N,512]^T ----------------
// 128(M) x 256(N) tile, BK=32, 8 waves (2x4), 512 threads, THREE LDS buffers,
// prefetch depth 2, counted vmcnt(3) steady state (T4), conflict-free 4-slot XOR swizzle.
// EPI 0: C -> O0 row-major. EPI 1 (NBLK=6): nb 0-1 Q (pre-scaled by 0.125*log2e for the
// exp2-domain softmax in k_attn), 2-3 K, 4-5 Vt-scatter.
template<int NBLK, int EPI>
__global__ __launch_bounds__(512, 4) void k_gemm(
    const unsigned short* __restrict__ A, const unsigned short* __restrict__ Bm,
    unsigned short* __restrict__ O0, unsigned short* __restrict__ O1,
    unsigned short* __restrict__ O2) {
  __shared__ unsigned short Ash[3][128 * 32];   // 24 KB
  __shared__ unsigned short Bsh[3][256 * 32];   // 48 KB
  const int tid = threadIdx.x;
  const int lane = tid & 63, w = tid >> 6;      // 8 waves
  const int lr = lane & 15, lg = lane >> 4;
  const int cpx = gridDim.x >> 3;
  const int bid = blockIdx.x;
  const int work = (bid & 7) * cpx + (bid >> 3);
  const int nb = work % NBLK, mb = work / NBLK;
  const int m0 = mb * 128, n0 = nb * 256;
  const int wr = w >> 2, wc = w & 3;            // wave tile: 64 rows x 64 cols

  const int sr = lane >> 2;
  const int sg8 = ((lane & 3) ^ ((lane >> 3) & 3)) * 8;
  const unsigned short* gA  = A  + (size_t)(m0 + w * 16 + sr) * D + sg8;
  const unsigned short* gB0 = Bm + (size_t)(n0 + w * 16 + sr) * D + sg8;
  const unsigned short* gB1 = Bm + (size_t)(n0 + 128 + w * 16 + sr) * D + sg8;

  auto stage = [&](int kt, int b) {
    GLL16(gA  + kt * 32, &Ash[b][w * 512]);
    GLL16(gB0 + kt * 32, &Bsh[b][w * 512]);
    GLL16(gB1 + kt * 32, &Bsh[b][(128 + w * 16) * 32]);
  };

  f32x4 acc[4][4];
  #pragma unroll
  for (int m = 0; m < 4; ++m)
    #pragma unroll
    for (int n = 0; n < 4; ++n) acc[m][n] = (f32x4){0.f, 0.f, 0.f, 0.f};

  stage(0, 0);
  stage(1, 1);

  const int rdsw = (lg ^ ((lr >> 1) & 3)) * 8;   // conflict-free read slot

#define GSTEP(KT, WN) { \
    asm volatile("s_waitcnt vmcnt(" #WN ")" ::: "memory"); \
    __builtin_amdgcn_s_barrier(); \
    if ((KT) + 2 < 16) stage((KT) + 2, ((KT) + 2) % 3); \
    const unsigned short* Ac = Ash[(KT) % 3]; \
    const unsigned short* Bc = Bsh[(KT) % 3]; \
    short8 af[4], bf[4]; \
    _Pragma("unroll") \
    for (int m = 0; m < 4; ++m) \
      af[m] = *(const short8*)&Ac[(wr * 64 + m * 16 + lr) * 32 + rdsw]; \
    _Pragma("unroll") \
    for (int n = 0; n < 4; ++n) \
      bf[n] = *(const short8*)&Bc[(wc * 64 + n * 16 + lr) * 32 + rdsw]; \
    __builtin_amdgcn_s_setprio(1); \
    _Pragma("unroll") \
    for (int m = 0; m < 4; ++m) \
      _Pragma("unroll") \
      for (int n = 0; n < 4; ++n) \
        acc[m][n] = __builtin_amdgcn_mfma_f32_16x16x32_bf16(af[m], bf[n], acc[m][n], 0, 0, 0); \
    __builtin_amdgcn_s_setprio(0); \
  }

  GSTEP(0, 3)  GSTEP(1, 3)  GSTEP(2, 3)  GSTEP(3, 3)
  GSTEP(4, 3)  GSTEP(5, 3)  GSTEP(6, 3)  GSTEP(7, 3)
  GSTEP(8, 3)  GSTEP(9, 3)  GSTEP(10, 3) GSTEP(11, 3)
  GSTEP(12, 3) GSTEP(13, 3) GSTEP(14, 3) GSTEP(15, 0)
#undef GSTEP

  // ---- epilogue ----
  if (EPI == 1 && nb >= 4) {
    #pragma unroll
    for (int m = 0; m < 4; ++m) {
      #pragma unroll
      for (int n = 0; n < 4; ++n) {
        int e = (n0 - 1024) + wc * 64 + n * 16 + lr;
        int grow = m0 + wr * 64 + m * 16 + lg * 4;
        int bc = grow >> 9, key = grow & 511;
        ushort4 pk;
        pk.x = f2bf(acc[m][n][0]); pk.y = f2bf(acc[m][n][1]);
        pk.z = f2bf(acc[m][n][2]); pk.w = f2bf(acc[m][n][3]);
        *(ushort4*)&O2[(size_t)(bc * 512 + e) * 512 + key] = pk;
      }
    }
  } else {
    unsigned short* Od = O0;
    int cshift = 0;
    // Q output pre-scale: 0.125 (1/sqrt(64)) * log2(e) for exp2-domain softmax
    float cs = (EPI == 1 && nb < 2) ? 0.1803368801f : 1.0f;
    if (EPI == 1 && nb >= 2) { Od = O1; cshift = 512; }
    #pragma unroll
    for (int m = 0; m < 4; ++m) {
      #pragma unroll
      for (int n = 0; n < 4; ++n) {
        int col = n0 + wc * 64 + n * 16 + lr - cshift;
        #pragma unroll
        for (int r = 0; r < 4; ++r) {
          int row = m0 + wr * 64 + m * 16 + lg * 4 + r;
          Od[(size_t)row * D + col] = f2bf(acc[m][n][r] * cs);
        }
      }
    }
  }
}

// ---------------- K3: flash-style local attention, swapped 32x32 MFMA ----------------
// grid = 1024 = 64 chunks x 8 heads x 2 q-halves; block = 512 (8 waves x 32 q-rows).
// exp2-domain softmax via raw v_exp_f32 (Q pre-scaled), defer-max THR=8 (T13),
// cross-half reductions via __shfl_xor(.,32) (verified r5-r7; permlane xhalf was the r8 bug).
__global__ __launch_bounds__(512, 4) void k_attn(
    const unsigned short* __restrict__ Q, const unsigned short* __restrict__ K,
    const unsigned short* __restrict__ Vt, unsigned short* __restrict__ attn_out) {
  __shared__ char lds[3][16384];   // buf: [0,8K) K-tile [64keys][64d], [8K,16K) V-tile [64e][64k]
  const int tid = threadIdx.x;
  const int lane = tid & 63, w = tid >> 6;
  const int l31 = lane & 31, hl = lane >> 5;
  int work = ((blockIdx.x & 7) << 7) + (blockIdx.x >> 3);   // XCD-chunked swizzle (1024%8==0)
  int qh = work & 1, h = (work >> 1) & 7, bc = work >> 4;
  int qbase = bc * 512 + qh * 256 + w * 32;

  // Q B-frags: B[q=l31][k = ks*16 + hl*8 + j]  (Q pre-scaled by 0.125*log2e in k_gemm)
  short8 qf[4];
  {
    const unsigned short* qp = Q + (size_t)(qbase + l31) * D + h * 64 + hl * 8;
    #pragma unroll
    for (int ks = 0; ks < 4; ++ks) qf[ks] = *(const short8*)(qp + ks * 16);
  }

  // staging: LDS[row][slot] = G[row][slot ^ f(row)], f(row) = (row + row>>3) & 7
  const int lr3 = lane >> 3;
  const int srow = w * 8 + lr3;                      // 0..63
  const int sq = (lane & 7) ^ ((lr3 + w) & 7);       // source quad = slot ^ f(row)
  const unsigned short* gK = K  + (size_t)(bc * 512 + srow) * D + h * 64 + sq * 8;
  const unsigned short* gV = Vt + (size_t)(bc * 512 + h * 64 + srow) * D + sq * 8;
  auto STAGE = [&](int T, int B) {
    GLL16(gK + (size_t)(T) * 64 * D, &lds[B][w * 1024]);
    GLL16(gV + (T) * 64,             &lds[B][8192 + w * 1024]);
  };

  f32x16 oA, oB;
  #pragma unroll
  for (int i = 0; i < 16; ++i) { oA[i] = 0.f; oB[i] = 0.f; }
  float mrun = -3e38f, lrun = 0.f;
  const int f0 = (l31 + (l31 >> 3)) & 7;   // f(row l31)
  const int f1 = (f0 + 4) & 7;             // f(row 32+l31)

  STAGE(0, 0);
  STAGE(1, 1);

  #pragma unroll
  for (int t = 0; t < 8; ++t) {
    if (t == 0 || t == 7) asm volatile("s_waitcnt vmcnt(0)" ::: "memory");
    else                  asm volatile("s_waitcnt vmcnt(2)" ::: "memory");
    __builtin_amdgcn_s_barrier();
    if (t < 6) STAGE(t + 2, (t + 2) % 3);
    const char* kb = lds[t % 3];
    const char* vb = lds[t % 3] + 8192;

    // ---- QK^T swapped: S^T[key][q] = mfma(A=K, B=Q) ----
    f32x16 sA, sB;
    #pragma unroll
    for (int i = 0; i < 16; ++i) { sA[i] = 0.f; sB[i] = 0.f; }
    #pragma unroll
    for (int ks = 0; ks < 4; ++ks) {
      int c = ks * 2 + hl;
      short8 kf0 = *(const short8*)(kb + l31 * 128 + ((c ^ f0) << 4));
      short8 kf1 = *(const short8*)(kb + (32 + l31) * 128 + ((c ^ f1) << 4));
      sA = __builtin_amdgcn_mfma_f32_32x32x16_bf16(kf0, qf[ks], sA, 0, 0, 0);
      sB = __builtin_amdgcn_mfma_f32_32x32x16_bf16(kf1, qf[ks], sB, 0, 0, 0);
    }

    // ---- online softmax, exp2 domain (lane owns q = l31; partner lane^32 = other keys) ----
    float pm = fmaxf(sA[0], sA[1]);
    #pragma unroll
    for (int i = 2; i < 16; i += 2) pm = fmaxf(pm, fmaxf(sA[i], sA[i + 1]));   // v_max3
    #pragma unroll
    for (int i = 0; i < 16; i += 2) pm = fmaxf(pm, fmaxf(sB[i], sB[i + 1]));
    pm = fmaxf(pm, __shfl_xor(pm, 32));
    if (!__all(pm - mrun <= 8.f)) {     // defer-max (T13): rescale only on real growth
      float mnew = fmaxf(mrun, pm);
      float alpha = fexp2(mrun - mnew); // first tile: exp2(-huge) = 0
      mrun = mnew;
      lrun *= alpha;
      #pragma unroll
      for (int i = 0; i < 16; ++i) { oA[i] *= alpha; oB[i] *= alpha; }
    }
    float ls = 0.f;
    #pragma unroll
    for (int i = 0; i < 16; ++i) { float p = fexp2(sA[i] - mrun); sA[i] = p; ls += p; }
    #pragma unroll
    for (int i = 0; i < 16; ++i) { float p = fexp2(sB[i] - mrun); sB[i] = p; ls += p; }
    ls += __shfl_xor(ls, 32);
    lrun += ls;

    // ---- P repack to PV fragments: cvt_pk + permlane32_swap (T12) ----
    unsigned dA[8], dB[8];
    #pragma unroll
    for (int i = 0; i < 8; ++i) {
      dA[i] = cvtpk(sA[2 * i], sA[2 * i + 1]);
      dB[i] = cvtpk(sB[2 * i], sB[2 * i + 1]);
    }
    plswap(dA[0], dA[2]); plswap(dA[1], dA[3]);
    plswap(dA[4], dA[6]); plswap(dA[5], dA[7]);
    plswap(dB[0], dB[2]); plswap(dB[1], dB[3]);
    plswap(dB[4], dB[6]); plswap(dB[5], dB[7]);
    short8 pf[4] = { mk8(dA[0], dA[1], dA[2], dA[3]), mk8(dA[4], dA[5], dA[6], dA[7]),
                     mk8(dB[0], dB[1], dB[2], dB[3]), mk8(dB[4], dB[5], dB[6], dB[7]) };

    // ---- PV swapped: O^T[e][q] += mfma(A=V, B=P) ----
    #pragma unroll
    for (int k4 = 0; k4 < 4; ++k4) {
      int c = k4 * 2 + hl;
      short8 vf0 = *(const short8*)(vb + l31 * 128 + ((c ^ f0) << 4));
      short8 vf1 = *(const short8*)(vb + (32 + l31) * 128 + ((c ^ f1) << 4));
      oA = __builtin_amdgcn_mfma_f32_32x32x16_bf16(vf0, pf[k4], oA, 0, 0, 0);
      oB = __builtin_amdgcn_mfma_f32_32x32x16_bf16(vf1, pf[k4], oB, 0, 0, 0);
    }
  }

  // ---- epilogue: normalize, transpose O^T -> O via per-wave LDS region ----
  __syncthreads();                      // all waves done reading KV bufs
  float inv = 1.f / lrun;
  const int x7 = l31 & 7;
  char* tr = &lds[0][0] + w * 4096;     // [32 q][64 e] bf16, XOR-swizzled rows
  #pragma unroll
  for (int r = 0; r < 16; ++r) {
    int e0 = (r & 3) + 8 * (r >> 2) + 4 * hl;
    *(unsigned short*)(tr + ((l31 * 128 + e0 * 2) ^ (x7 << 4)))        = f2bf(oA[r] * inv);
    *(unsigned short*)(tr + ((l31 * 128 + (32 + e0) * 2) ^ (x7 << 4))) = f2bf(oB[r] * inv);
  }
  unsigned short* op = attn_out + (size_t)(qbase + l31) * D + h * 64 + hl * 32;
  #pragma unroll
  for (int s = 0; s < 4; ++s) {
    int slot = (hl * 4 + s) ^ x7;
    short8 v = *(const short8*)(tr + l31 * 128 + slot * 16);
    *(short8*)(op + s * 8) = v;
  }
}

// ---------------- K4b: per-chunk mean -> summaries fp32 [64][512] ----------------
__global__ __launch_bounds__(256) void k_mean(const unsigned short* __restrict__ lout,
                                              float* __restrict__ summ) {
  int bc = blockIdx.x;
  int col = blockIdx.y * 256 + threadIdx.x;
  const unsigned short* p = lout + (size_t)bc * 512 * 512 + col;
  float s = 0.f;
  #pragma unroll 8
  for (int r = 0; r < 512; ++r) s += bf2f(p[(size_t)r * 512]);
  summ[bc * 512 + col] = s * (1.f / 512.f);
}

// ---------------- K5a: sg = summaries @ Wg.T (fp32, tiny) ----------------
__global__ __launch_bounds__(256) void k_sg(const float* __restrict__ summ,
                                            const float* __restrict__ Wg,
                                            float* __restrict__ sg) {
  __shared__ float srow[512];
  int m = blockIdx.x >> 1, half = blockIdx.x & 1;
  for (int i = threadIdx.x; i < 512; i += 256) srow[i] = summ[m * 512 + i];
  __syncthreads();
  int n = half * 256 + threadIdx.x;
  const float* wr = Wg + (size_t)n * 512;
  float s = 0.f;
  #pragma unroll 8
  for (int kk = 0; kk < 512; ++kk) s += srow[kk] * wr[kk];
  sg[m * 512 + n] = s;
}

// ---------------- K5b: cross-chunk attention (fp32, tiny) ----------------
__global__ __launch_bounds__(256) void k_gattn(const float* __restrict__ sg,
                                               float* __restrict__ gctx) {
  __shared__ float qs[32][64];
  __shared__ float sc[32][32];
  int b = blockIdx.x >> 3, h = blockIdx.x & 7;
  int tid = threadIdx.x;
  for (int i = tid; i < 2048; i += 256) {
    int r = i >> 6, e = i & 63;
    qs[r][e] = sg[(size_t)(b * 32 + r) * 512 + h * 64 + e];
  }
  __syncthreads();
  for (int p = tid; p < 1024; p += 256) {
    int qi = p >> 5, ki = p & 31;
    float s = 0.f;
    #pragma unroll 8
    for (int e = 0; e < 64; ++e) s += qs[qi][e] * qs[ki][e];
    sc[qi][ki] = s * 0.125f;
  }
  __syncthreads();
  if (tid < 32) {
    float mx = -1e30f;
    for (int k2 = 0; k2 < 32; ++k2) mx = fmaxf(mx, sc[tid][k2]);
    float sm = 0.f;
    for (int k2 = 0; k2 < 32; ++k2) { float p = __expf(sc[tid][k2] - mx); sc[tid][k2] = p; sm += p; }
    float iv = 1.f / sm;
    for (int k2 = 0; k2 < 32; ++k2) sc[tid][k2] *= iv;
  }
  __syncthreads();
  for (int i = tid; i < 2048; i += 256) {
    int r = i >> 6, e = i & 63;
    float o = 0.f;
    #pragma unroll 8
    for (int k2 = 0; k2 < 32; ++k2) o += sc[r][k2] * qs[k2][e];
    gctx[(size_t)(b * 32 + r) * 512 + h * 64 + e] = o;
  }
}

// ---------------- K6: out = local_out + broadcast(gctx), fp32 output ----------------
__global__ __launch_bounds__(256) void k_final(const unsigned short* __restrict__ lout,
                                               const float* __restrict__ gctx,
                                               float* __restrict__ out) {
  size_t idx = (size_t)blockIdx.x * 256 + threadIdx.x;
  size_t i = idx * 4;
  int c = (int)(i & 511);
  int bcg = (int)(i >> 18);
  ushort4 lv = *(const ushort4*)(lout + i);
  float4 g = *(const float4*)(gctx + (size_t)bcg * 512 + c);
  float4 o;
  o.x = bf2f(lv.x) + g.x;
  o.y = bf2f(lv.y) + g.y;
  o.z = bf2f(lv.z) + g.z;
  o.w = bf2f(lv.w) + g.w;
  *(float4*)(out + i) = o;
}

extern "C" void kernel_launch(void* const* d_in, const int* in_sizes, int n_in,
                              void* d_out, int out_size, void* d_ws, size_t ws_size,
                              hipStream_t stream) {
  const float* x  = (const float*)d_in[0];
  const float* Wq = (const float*)d_in[1];
  const float* Wk = (const float*)d_in[2];
  const float* Wv = (const float*)d_in[3];
  const float* Wo = (const float*)d_in[4];
  const float* Wg = (const float*)d_in[5];
  float* out = (float*)d_out;

  char* ws = (char*)d_ws;
  unsigned short* xb   = (unsigned short*)(ws);                 // 32 MB  [A]
  unsigned short* q    = (unsigned short*)(ws + 33554432);      // 32 MB  [B]
  unsigned short* kb   = (unsigned short*)(ws + 67108864);      // 32 MB  [C]
  unsigned short* vt   = (unsigned short*)(ws + 100663296);     // 32 MB  [D]
  unsigned short* wqkv = (unsigned short*)(ws + 134217728);     // 1.5 MB
  unsigned short* wo_b = (unsigned short*)(ws + 135790592);     // 0.5 MB
  float* summ = (float*)(ws + 136314880);                       // 128 KB
  float* sgp  = (float*)(ws + 136445952);                       // 128 KB
  float* gctx = (float*)(ws + 136577024);                       // 128 KB
  unsigned short* attn_out = xb;   // region A reused (xb dead after k_qkv)
  unsigned short* local_bf = q;    // region B reused (q dead after k_attn)

  k_convert<<<17408, 256, 0, stream>>>(x, Wq, Wk, Wv, Wo, xb, wqkv, wo_b);
  // QKV: M=32768, N=1536 -> 256 x 6 = 1536 blocks, 512 threads
  k_gemm<6, 1><<<1536, 512, 0, stream>>>(xb, wqkv, q, kb, vt);
  k_attn<<<1024, 512, 0, stream>>>(q, kb, vt, attn_out);
  // Wo: M=32768, N=512 -> 256 x 2 = 512 blocks, 512 threads
  k_gemm<2, 0><<<512, 512, 0, stream>>>(attn_out, wo_b, local_bf, nullptr, nullptr);
  k_mean<<<dim3(64, 2), 256, 0, stream>>>(local_bf, summ);
  k_sg<<<128, 256, 0, stream>>>(summ, Wg, sgp);
  k_gattn<<<16, 256, 0, stream>>>(sgp, gctx);
  k_final<<<16384, 256, 0, stream>>>(local_bf, gctx, out);
}

// Round 11
// 230.439 us; speedup vs baseline: 1.0508x; 1.0048x over previous
//
#include <hip/hip_runtime.h>

typedef __attribute__((ext_vector_type(8))) short short8;
typedef __attribute__((ext_vector_type(4))) float f32x4;
typedef __attribute__((ext_vector_type(16))) float f32x16;

#define DEV static __device__ __forceinline__

DEV float bf2f(unsigned short u) {
  union { unsigned int u32; float f; } v; v.u32 = ((unsigned int)u) << 16; return v.f;
}
DEV unsigned short f2bf(float f) {
  union { float f; unsigned int u; } v; v.f = f;
  unsigned int r = v.u + 0x7fffu + ((v.u >> 16) & 1u);
  return (unsigned short)(r >> 16);
}
DEV unsigned cvtpk(float lo, float hi) {
  unsigned r;
  asm("v_cvt_pk_bf16_f32 %0, %1, %2" : "=v"(r) : "v"(lo), "v"(hi));
  return r;
}
DEV void plswap(unsigned &a, unsigned &b) {
  asm("v_permlane32_swap_b32 %0, %1" : "+v"(a), "+v"(b));
}
DEV short8 mk8(unsigned a, unsigned b, unsigned c, unsigned d) {
  union { unsigned u[4]; short8 v; } x;
  x.u[0] = a; x.u[1] = b; x.u[2] = c; x.u[3] = d; return x.v;
}
// raw v_exp_f32 (= 2^x); libm exp2f expands to a slow denormal-safe sequence (r7 lesson)
DEV float fexp2(float x) {
  float r;
  asm("v_exp_f32 %0, %1" : "=v"(r) : "v"(x));
  return r;
}

// async global->LDS, 16B per lane; LDS dest is wave-uniform base + lane*16
#define GLL16(g, l) __builtin_amdgcn_global_load_lds( \
    (const __attribute__((address_space(1))) void*)(g), \
    (__attribute__((address_space(3))) void*)(l), 16, 0, 0)

constexpr int D  = 512;
constexpr int BT = 32768;   // B*T rows

// ---------------- K1: fp32 -> bf16 conversion (x, Wq|Wk|Wv concat, Wo) ----------------
__global__ __launch_bounds__(256) void k_convert(
    const float* __restrict__ x, const float* __restrict__ Wq, const float* __restrict__ Wk,
    const float* __restrict__ Wv, const float* __restrict__ Wo,
    unsigned short* __restrict__ xb, unsigned short* __restrict__ wqkv,
    unsigned short* __restrict__ wo_b) {
  int idx = blockIdx.x * 256 + threadIdx.x;
  const int NX4 = (BT * D) / 4;      // 4,194,304
  const float* src; unsigned short* dst; size_t i4;
  if (idx < NX4) {
    src = x; dst = xb; i4 = (size_t)idx * 4;
  } else {
    int t = idx - NX4;
    int w = t >> 16;                 // NW4 = 512*512/4 = 65536
    int within = t & 65535;
    src = (w == 0) ? Wq : (w == 1) ? Wk : (w == 2) ? Wv : Wo;
    dst = (w < 3) ? (wqkv + (size_t)w * D * D) : wo_b;
    i4 = (size_t)within * 4;
  }
  float4 v = *(const float4*)(src + i4);
  ushort4 o; o.x = f2bf(v.x); o.y = f2bf(v.y); o.z = f2bf(v.z); o.w = f2bf(v.w);
  *(ushort4*)(dst + i4) = o;
}

// ---------------- GEMM v4: 256x256 tile, BK=64, 4-phase/K-tile, counted vmcnt ----------------
// 8 waves (2M x 4N), wave tile 128x64 (acc[8][4]). LDS 128 KB: per matrix per buffer two
// k-sub planes [256 rows][32 cols] (row = 64 B; reads provably conflict-free unswizzled).
// Staging: 8 GLL16 (8 KB each) per K-tile, 2 per phase; sync = vmcnt(4)+s_barrier twice
// per K-tile (entry + mid). Loads stay in flight across barriers (T4) — no drain in loop.
// EPI 0: C -> O0 row-major. EPI 1 (NBLK=6): nb 0-1 Q (pre-scaled 0.125*log2e), 2-3 K,
// 4-5 Vt-scatter (ushort4 key-packed).
template<int NBLK, int EPI>
__global__ __launch_bounds__(512, 2) void k_gemm(
    const unsigned short* __restrict__ A, const unsigned short* __restrict__ Bm,
    unsigned short* __restrict__ O0, unsigned short* __restrict__ O1,
    unsigned short* __restrict__ O2) {
  __shared__ unsigned short sh[65536];   // 128 KB: A planes [0,32768), B planes [32768,65536)
  const int tid = threadIdx.x;
  const int lane = tid & 63, w = tid >> 6;
  const int lr = lane & 15, lg = lane >> 4;
  // bijective XCD-chunked swizzle (gridDim % 8 == 0 for both instantiations)
  const int cpx = gridDim.x >> 3;
  const int work = (blockIdx.x & 7) * cpx + (blockIdx.x >> 3);
  const int nb = work % NBLK, mb = work / NBLK;
  const int m0 = mb * 256, n0 = nb * 256;
  const int wr = w >> 2, wc = w & 3;     // wave tile: 128 rows x 64 cols

  // staging map: one GLL16 by all 512 threads = 128 rows x 32 cols (8 KB) of one k-plane half
  const int srow = tid >> 2;             // 0..127
  const int scol = (tid & 3) * 8;
  const unsigned short* gA = A  + (size_t)(m0 + srow) * D + scol;
  const unsigned short* gB = Bm + (size_t)(n0 + srow) * D + scol;

  f32x4 acc[8][4];
  #pragma unroll
  for (int m = 0; m < 8; ++m)
    #pragma unroll
    for (int n = 0; n < 4; ++n) acc[m][n] = (f32x4){0.f, 0.f, 0.f, 0.f};

  // prologue: stage K-tile 0 into buf 0. Order matters: ks0 planes (A then B) first,
  // so the uniform entry vmcnt(4) leaves exactly the ks1 calls outstanding.
  GLL16(gA,                 &sh[w * 512]);                         // A ks0 hc0
  GLL16(gA + 128 * D,       &sh[4096 + w * 512]);                  // A ks0 hc1
  GLL16(gB,                 &sh[32768 + w * 512]);                 // B ks0 hc0
  GLL16(gB + 128 * D,       &sh[32768 + 4096 + w * 512]);          // B ks0 hc1
  GLL16(gA + 32,            &sh[8192 + w * 512]);                  // A ks1 hc0
  GLL16(gA + 128 * D + 32,  &sh[8192 + 4096 + w * 512]);           // A ks1 hc1
  GLL16(gB + 32,            &sh[32768 + 8192 + w * 512]);          // B ks1 hc0
  GLL16(gB + 128 * D + 32,  &sh[32768 + 8192 + 4096 + w * 512]);   // B ks1 hc1

  short8 bfr[4];

  // phase (MH, KS) of tile T: optionally stage (matrix SM, plane SKS) of tile T+1 into buf^1,
  // then read frags and run 16 MFMA. B-frags read once per KS (MH==0), cached for MH==1.
#define PHASE(T, MH, KS, SM, SKS) { \
    if ((T) < 7) { \
      const unsigned short* g = (SM) ? gB : gA; \
      const int sb = ((SM) ? 32768 : 0) + ((((T) & 1) ^ 1) * 2 + (SKS)) * 8192; \
      GLL16(g + ((T) + 1) * 64 + (SKS) * 32,           &sh[sb + w * 512]); \
      GLL16(g + 128 * D + ((T) + 1) * 64 + (SKS) * 32, &sh[sb + 4096 + w * 512]); \
    } \
    const int aB = (((T) & 1) * 2 + (KS)) * 8192; \
    const int bB = 32768 + (((T) & 1) * 2 + (KS)) * 8192; \
    if ((MH) == 0) { \
      _Pragma("unroll") \
      for (int n = 0; n < 4; ++n) \
        bfr[n] = *(const short8*)&sh[bB + (wc * 64 + n * 16 + lr) * 32 + lg * 8]; \
    } \
    short8 afr[4]; \
    _Pragma("unroll") \
    for (int mf = 0; mf < 4; ++mf) \
      afr[mf] = *(const short8*)&sh[aB + (wr * 128 + (MH) * 64 + mf * 16 + lr) * 32 + lg * 8]; \
    __builtin_amdgcn_s_setprio(1); \
    _Pragma("unroll") \
    for (int mf = 0; mf < 4; ++mf) \
      _Pragma("unroll") \
      for (int n = 0; n < 4; ++n) \
        acc[(MH) * 4 + mf][n] = __builtin_amdgcn_mfma_f32_16x16x32_bf16(afr[mf], bfr[n], acc[(MH) * 4 + mf][n], 0, 0, 0); \
    __builtin_amdgcn_s_setprio(0); \
  }

  #pragma unroll
  for (int t = 0; t < 8; ++t) {
    // entry: tile t's ks0 planes (4 oldest calls) landed; ks1 (4 newer) may fly on
    asm volatile("s_waitcnt vmcnt(4)" ::: "memory");
    __builtin_amdgcn_s_barrier();
    PHASE(t, 0, 0, 0, 0)   // compute m-half 0, ksub 0 | stage A-ks0 of t+1
    PHASE(t, 1, 0, 1, 0)   // compute m-half 1, ksub 0 | stage B-ks0 of t+1
    // mid: tile t's ks1 planes landed (4 newer = t+1's ks0 calls, except last tile)
    if (t < 7) asm volatile("s_waitcnt vmcnt(4)" ::: "memory");
    else       asm volatile("s_waitcnt vmcnt(0)" ::: "memory");
    __builtin_amdgcn_s_barrier();
    PHASE(t, 0, 1, 0, 1)   // compute m-half 0, ksub 1 | stage A-ks1 of t+1
    PHASE(t, 1, 1, 1, 1)   // compute m-half 1, ksub 1 | stage B-ks1 of t+1
  }
#undef PHASE

  // ---- epilogue (verified r6-r9 C/D layout; 8 m-frags) ----
  if (EPI == 1 && nb >= 4) {
    #pragma unroll
    for (int mf = 0; mf < 8; ++mf) {
      #pragma unroll
      for (int n = 0; n < 4; ++n) {
        int e = (n0 - 1024) + wc * 64 + n * 16 + lr;
        int grow = m0 + wr * 128 + mf * 16 + lg * 4;
        int bc = grow >> 9, key = grow & 511;
        ushort4 pk;
        pk.x = f2bf(acc[mf][n][0]); pk.y = f2bf(acc[mf][n][1]);
        pk.z = f2bf(acc[mf][n][2]); pk.w = f2bf(acc[mf][n][3]);
        *(ushort4*)&O2[(size_t)(bc * 512 + e) * 512 + key] = pk;
      }
    }
  } else {
    unsigned short* Od = O0;
    int cshift = 0;
    // Q output pre-scale: 0.125 (1/sqrt(64)) * log2(e) for exp2-domain softmax
    float cs = (EPI == 1 && nb < 2) ? 0.1803368801f : 1.0f;
    if (EPI == 1 && nb >= 2) { Od = O1; cshift = 512; }
    #pragma unroll
    for (int mf = 0; mf < 8; ++mf) {
      #pragma unroll
      for (int n = 0; n < 4; ++n) {
        int col = n0 + wc * 64 + n * 16 + lr - cshift;
        #pragma unroll
        for (int r = 0; r < 4; ++r) {
          int row = m0 + wr * 128 + mf * 16 + lg * 4 + r;
          Od[(size_t)row * D + col] = f2bf(acc[mf][n][r] * cs);
        }
      }
    }
  }
}

// ---------------- K3: flash-style local attention, swapped 32x32 MFMA ----------------
// grid = 1024 = 64 chunks x 8 heads x 2 q-halves; block = 512 (8 waves x 32 q-rows).
__global__ __launch_bounds__(512, 4) void k_attn(
    const unsigned short* __restrict__ Q, const unsigned short* __restrict__ K,
    const unsigned short* __restrict__ Vt, unsigned short* __restrict__ attn_out) {
  __shared__ char lds[3][16384];   // buf: [0,8K) K-tile [64keys][64d], [8K,16K) V-tile [64e][64k]
  const int tid = threadIdx.x;
  const int lane = tid & 63, w = tid >> 6;
  const int l31 = lane & 31, hl = lane >> 5;
  int work = ((blockIdx.x & 7) << 7) + (blockIdx.x >> 3);   // XCD-chunked swizzle (1024%8==0)
  int qh = work & 1, h = (work >> 1) & 7, bc = work >> 4;
  int qbase = bc * 512 + qh * 256 + w * 32;

  // Q B-frags: B[q=l31][k = ks*16 + hl*8 + j]  (Q pre-scaled by 0.125*log2e in k_gemm)
  short8 qf[4];
  {
    const unsigned short* qp = Q + (size_t)(qbase + l31) * D + h * 64 + hl * 8;
    #pragma unroll
    for (int ks = 0; ks < 4; ++ks) qf[ks] = *(const short8*)(qp + ks * 16);
  }

  // staging: LDS[row][slot] = G[row][slot ^ f(row)], f(row) = (row + row>>3) & 7
  const int lr3 = lane >> 3;
  const int srow = w * 8 + lr3;                      // 0..63
  const int sq = (lane & 7) ^ ((lr3 + w) & 7);       // source quad = slot ^ f(row)
  const unsigned short* gK = K  + (size_t)(bc * 512 + srow) * D + h * 64 + sq * 8;
  const unsigned short* gV = Vt + (size_t)(bc * 512 + h * 64 + srow) * D + sq * 8;
  auto STAGE = [&](int T, int B) {
    GLL16(gK + (size_t)(T) * 64 * D, &lds[B][w * 1024]);
    GLL16(gV + (T) * 64,             &lds[B][8192 + w * 1024]);
  };

  f32x16 oA, oB;
  #pragma unroll
  for (int i = 0; i < 16; ++i) { oA[i] = 0.f; oB[i] = 0.f; }
  float mrun = -3e38f, lrun = 0.f;
  const int f0 = (l31 + (l31 >> 3)) & 7;   // f(row l31)
  const int f1 = (f0 + 4) & 7;             // f(row 32+l31)

  STAGE(0, 0);
  STAGE(1, 1);

  #pragma unroll
  for (int t = 0; t < 8; ++t) {
    if (t == 0 || t == 7) asm volatile("s_waitcnt vmcnt(0)" ::: "memory");
    else                  asm volatile("s_waitcnt vmcnt(2)" ::: "memory");
    __builtin_amdgcn_s_barrier();
    if (t < 6) STAGE(t + 2, (t + 2) % 3);
    const char* kb = lds[t % 3];
    const char* vb = lds[t % 3] + 8192;

    // ---- QK^T swapped: S^T[key][q] = mfma(A=K, B=Q) ----
    f32x16 sA, sB;
    #pragma unroll
    for (int i = 0; i < 16; ++i) { sA[i] = 0.f; sB[i] = 0.f; }
    #pragma unroll
    for (int ks = 0; ks < 4; ++ks) {
      int c = ks * 2 + hl;
      short8 kf0 = *(const short8*)(kb + l31 * 128 + ((c ^ f0) << 4));
      short8 kf1 = *(const short8*)(kb + (32 + l31) * 128 + ((c ^ f1) << 4));
      sA = __builtin_amdgcn_mfma_f32_32x32x16_bf16(kf0, qf[ks], sA, 0, 0, 0);
      sB = __builtin_amdgcn_mfma_f32_32x32x16_bf16(kf1, qf[ks], sB, 0, 0, 0);
    }

    // ---- online softmax, exp2 domain ----
    float pm = fmaxf(sA[0], sA[1]);
    #pragma unroll
    for (int i = 2; i < 16; i += 2) pm = fmaxf(pm, fmaxf(sA[i], sA[i + 1]));   // v_max3
    #pragma unroll
    for (int i = 0; i < 16; i += 2) pm = fmaxf(pm, fmaxf(sB[i], sB[i + 1]));
    pm = fmaxf(pm, __shfl_xor(pm, 32));
    if (!__all(pm - mrun <= 8.f)) {     // defer-max (T13)
      float mnew = fmaxf(mrun, pm);
      float alpha = fexp2(mrun - mnew); // first tile: exp2(-huge) = 0
      mrun = mnew;
      lrun *= alpha;
      #pragma unroll
      for (int i = 0; i < 16; ++i) { oA[i] *= alpha; oB[i] *= alpha; }
    }
    float ls = 0.f;
    #pragma unroll
    for (int i = 0; i < 16; ++i) { float p = fexp2(sA[i] - mrun); sA[i] = p; ls += p; }
    #pragma unroll
    for (int i = 0; i < 16; ++i) { float p = fexp2(sB[i] - mrun); sB[i] = p; ls += p; }
    ls += __shfl_xor(ls, 32);
    lrun += ls;

    // ---- P repack to PV fragments: cvt_pk + permlane32_swap (T12) ----
    unsigned dA[8], dB[8];
    #pragma unroll
    for (int i = 0; i < 8; ++i) {
      dA[i] = cvtpk(sA[2 * i], sA[2 * i + 1]);
      dB[i] = cvtpk(sB[2 * i], sB[2 * i + 1]);
    }
    plswap(dA[0], dA[2]); plswap(dA[1], dA[3]);
    plswap(dA[4], dA[6]); plswap(dA[5], dA[7]);
    plswap(dB[0], dB[2]); plswap(dB[1], dB[3]);
    plswap(dB[4], dB[6]); plswap(dB[5], dB[7]);
    short8 pf[4] = { mk8(dA[0], dA[1], dA[2], dA[3]), mk8(dA[4], dA[5], dA[6], dA[7]),
                     mk8(dB[0], dB[1], dB[2], dB[3]), mk8(dB[4], dB[5], dB[6], dB[7]) };

    // ---- PV swapped: O^T[e][q] += mfma(A=V, B=P) ----
    #pragma unroll
    for (int k4 = 0; k4 < 4; ++k4) {
      int c = k4 * 2 + hl;
      short8 vf0 = *(const short8*)(vb + l31 * 128 + ((c ^ f0) << 4));
      short8 vf1 = *(const short8*)(vb + (32 + l31) * 128 + ((c ^ f1) << 4));
      oA = __builtin_amdgcn_mfma_f32_32x32x16_bf16(vf0, pf[k4], oA, 0, 0, 0);
      oB = __builtin_amdgcn_mfma_f32_32x32x16_bf16(vf1, pf[k4], oB, 0, 0, 0);
    }
  }

  // ---- epilogue: normalize, transpose O^T -> O via per-wave LDS region ----
  __syncthreads();
  float inv = 1.f / lrun;
  const int x7 = l31 & 7;
  char* tr = &lds[0][0] + w * 4096;     // [32 q][64 e] bf16, XOR-swizzled rows
  #pragma unroll
  for (int r = 0; r < 16; ++r) {
    int e0 = (r & 3) + 8 * (r >> 2) + 4 * hl;
    *(unsigned short*)(tr + ((l31 * 128 + e0 * 2) ^ (x7 << 4)))        = f2bf(oA[r] * inv);
    *(unsigned short*)(tr + ((l31 * 128 + (32 + e0) * 2) ^ (x7 << 4))) = f2bf(oB[r] * inv);
  }
  unsigned short* op = attn_out + (size_t)(qbase + l31) * D + h * 64 + hl * 32;
  #pragma unroll
  for (int s = 0; s < 4; ++s) {
    int slot = (hl * 4 + s) ^ x7;
    short8 v = *(const short8*)(tr + l31 * 128 + slot * 16);
    *(short8*)(op + s * 8) = v;
  }
}

// ---------------- K4b: per-chunk mean -> summaries fp32 [64][512] ----------------
__global__ __launch_bounds__(256) void k_mean(const unsigned short* __restrict__ lout,
                                              float* __restrict__ summ) {
  int bc = blockIdx.x;
  int col = blockIdx.y * 256 + threadIdx.x;
  const unsigned short* p = lout + (size_t)bc * 512 * 512 + col;
  float s = 0.f;
  #pragma unroll 8
  for (int r = 0; r < 512; ++r) s += bf2f(p[(size_t)r * 512]);
  summ[bc * 512 + col] = s * (1.f / 512.f);
}

// ---------------- K5a: sg = summaries @ Wg.T (fp32, tiny) ----------------
__global__ __launch_bounds__(256) void k_sg(const float* __restrict__ summ,
                                            const float* __restrict__ Wg,
                                            float* __restrict__ sg) {
  __shared__ float srow[512];
  int m = blockIdx.x >> 1, half = blockIdx.x & 1;
  for (int i = threadIdx.x; i < 512; i += 256) srow[i] = summ[m * 512 + i];
  __syncthreads();
  int n = half * 256 + threadIdx.x;
  const float* wr = Wg + (size_t)n * 512;
  float s = 0.f;
  #pragma unroll 8
  for (int kk = 0; kk < 512; ++kk) s += srow[kk] * wr[kk];
  sg[m * 512 + n] = s;
}

// ---------------- K5b: cross-chunk attention (fp32, tiny) ----------------
__global__ __launch_bounds__(256) void k_gattn(const float* __restrict__ sg,
                                               float* __restrict__ gctx) {
  __shared__ float qs[32][64];
  __shared__ float sc[32][32];
  int b = blockIdx.x >> 3, h = blockIdx.x & 7;
  int tid = threadIdx.x;
  for (int i = tid; i < 2048; i += 256) {
    int r = i >> 6, e = i & 63;
    qs[r][e] = sg[(size_t)(b * 32 + r) * 512 + h * 64 + e];
  }
  __syncthreads();
  for (int p = tid; p < 1024; p += 256) {
    int qi = p >> 5, ki = p & 31;
    float s = 0.f;
    #pragma unroll 8
    for (int e = 0; e < 64; ++e) s += qs[qi][e] * qs[ki][e];
    sc[qi][ki] = s * 0.125f;
  }
  __syncthreads();
  if (tid < 32) {
    float mx = -1e30f;
    for (int k2 = 0; k2 < 32; ++k2) mx = fmaxf(mx, sc[tid][k2]);
    float sm = 0.f;
    for (int k2 = 0; k2 < 32; ++k2) { float p = __expf(sc[tid][k2] - mx); sc[tid][k2] = p; sm += p; }
    float iv = 1.f / sm;
    for (int k2 = 0; k2 < 32; ++k2) sc[tid][k2] *= iv;
  }
  __syncthreads();
  for (int i = tid; i < 2048; i += 256) {
    int r = i >> 6, e = i & 63;
    float o = 0.f;
    #pragma unroll 8
    for (int k2 = 0; k2 < 32; ++k2) o += sc[r][k2] * qs[k2][e];
    gctx[(size_t)(b * 32 + r) * 512 + h * 64 + e] = o;
  }
}

// ---------------- K6: out = local_out + broadcast(gctx), fp32 output ----------------
__global__ __launch_bounds__(256) void k_final(const unsigned short* __restrict__ lout,
                                               const float* __restrict__ gctx,
                                               float* __restrict__ out) {
  size_t idx = (size_t)blockIdx.x * 256 + threadIdx.x;
  size_t i = idx * 4;
  int c = (int)(i & 511);
  int bcg = (int)(i >> 18);
  ushort4 lv = *(const ushort4*)(lout + i);
  float4 g = *(const float4*)(gctx + (size_t)bcg * 512 + c);
  float4 o;
  o.x = bf2f(lv.x) + g.x;
  o.y = bf2f(lv.y) + g.y;
  o.z = bf2f(lv.z) + g.z;
  o.w = bf2f(lv.w) + g.w;
  *(float4*)(out + i) = o;
}

extern "C" void kernel_launch(void* const* d_in, const int* in_sizes, int n_in,
                              void* d_out, int out_size, void* d_ws, size_t ws_size,
                              hipStream_t stream) {
  const float* x  = (const float*)d_in[0];
  const float* Wq = (const float*)d_in[1];
  const float* Wk = (const float*)d_in[2];
  const float* Wv = (const float*)d_in[3];
  const float* Wo = (const float*)d_in[4];
  const float* Wg = (const float*)d_in[5];
  float* out = (float*)d_out;

  char* ws = (char*)d_ws;
  unsigned short* xb   = (unsigned short*)(ws);                 // 32 MB  [A]
  unsigned short* q    = (unsigned short*)(ws + 33554432);      // 32 MB  [B]
  unsigned short* kb   = (unsigned short*)(ws + 67108864);      // 32 MB  [C]
  unsigned short* vt   = (unsigned short*)(ws + 100663296);     // 32 MB  [D]
  unsigned short* wqkv = (unsigned short*)(ws + 134217728);     // 1.5 MB
  unsigned short* wo_b = (unsigned short*)(ws + 135790592);     // 0.5 MB
  float* summ = (float*)(ws + 136314880);                       // 128 KB
  float* sgp  = (float*)(ws + 136445952);                       // 128 KB
  float* gctx = (float*)(ws + 136577024);                       // 128 KB
  unsigned short* attn_out = xb;   // region A reused (xb dead after k_qkv)
  unsigned short* local_bf = q;    // region B reused (q dead after k_attn)

  k_convert<<<17408, 256, 0, stream>>>(x, Wq, Wk, Wv, Wo, xb, wqkv, wo_b);
  // QKV: M=32768 -> 128 m-tiles x 6 n-tiles(256) = 768 blocks, 512 threads
  k_gemm<6, 1><<<768, 512, 0, stream>>>(xb, wqkv, q, kb, vt);
  k_attn<<<1024, 512, 0, stream>>>(q, kb, vt, attn_out);
  // Wo: M=32768 -> 128 x 2 = 256 blocks
  k_gemm<2, 0><<<256, 512, 0, stream>>>(attn_out, wo_b, local_bf, nullptr, nullptr);
  k_mean<<<dim3(64, 2), 256, 0, stream>>>(local_bf, summ);
  k_sg<<<128, 256, 0, stream>>>(summ, Wg, sgp);
  k_gattn<<<16, 256, 0, stream>>>(sgp, gctx);
  k_final<<<16384, 256, 0, stream>>>(local_bf, gctx, out);
}